// Round 21
// baseline (597.341 us; speedup 1.0000x reference)
//
#include <hip/hip_runtime.h>
#include <hip/hip_bf16.h>
#include <hip/hip_cooperative_groups.h>

namespace cg = cooperative_groups;

#define BB 64
#define TT 512
#define HH 256
#define EE 128
#define VV 32000
#define SS 128
#define LL 16

typedef __attribute__((ext_vector_type(8))) short bf16x8;
typedef __attribute__((ext_vector_type(4))) float f32x4;

static __device__ __forceinline__ unsigned short f2bf(float x) {
    unsigned int u = __float_as_uint(x);
    unsigned int r = (u + 0x7fffu + ((u >> 16) & 1u)) >> 16;
    return (unsigned short)r;
}

static __device__ __forceinline__ float ftanh(float x) {
    float y = __builtin_amdgcn_exp2f(x * 2.885390082f);
    return 1.f - 2.f * __builtin_amdgcn_rcpf(y + 1.f);
}

// ---------------- phase bodies (shared by mega + fallback kernels) ----------------
// smem is a float[5856] union; each phase carves what it needs.

__device__ __forceinline__ void pre_phase(int blk, int tid,
                                          const float* __restrict__ last_hidden,
                                          const float* __restrict__ attn_W,
                                          const float* __restrict__ attn_b,
                                          const int* __restrict__ z_tm1,
                                          const float* __restrict__ emb_W,
                                          const float* __restrict__ ctrl_W,
                                          const float* __restrict__ ctrl_b,
                                          const int* __restrict__ slot,
                                          float* __restrict__ hWp,
                                          float* __restrict__ embed,
                                          unsigned short* __restrict__ Bs,
                                          int* __restrict__ fidx,
                                          float* smem) {
    float* sh = smem;
    int* shi = (int*)(smem + 256);
    if (blk < 128) {
        int b = blk >> 1, kh = blk & 1;
        if (tid < 128) sh[tid] = last_hidden[b * HH + kh * 128 + tid];
        __syncthreads();
        const float4* wrow = (const float4*)(attn_W + (size_t)tid * (2 * HH) + kh * 128);
        float a0 = 0.f, a1 = 0.f;
        for (int k4 = 0; k4 < 32; k4 += 2) {
            float4 w0 = wrow[k4], w1 = wrow[k4 + 1];
            a0 += sh[k4*4+0]*w0.x + sh[k4*4+1]*w0.y + sh[k4*4+2]*w0.z + sh[k4*4+3]*w0.w;
            a1 += sh[k4*4+4]*w1.x + sh[k4*4+5]*w1.y + sh[k4*4+6]*w1.z + sh[k4*4+7]*w1.w;
        }
        float r = a0 + a1;
        if (kh == 0) r += attn_b[tid];
        hWp[kh * 16384 + b * 256 + tid] = r;
        __syncthreads();
    } else if (blk < 160) {
        int idx = (blk - 128) * 256 + tid;  // 8192 total
        int lane = idx & 63;
        int gt = (idx >> 6) & 15;
        int ks = idx >> 10;
        int col = gt * 16 + (lane & 15);
        int k0 = ks * 32 + (lane >> 4) * 8;
        const float* src = attn_W + (size_t)col * (2 * HH) + HH + k0;
        unsigned int p0 = f2bf(src[0]) | ((unsigned int)f2bf(src[1]) << 16);
        unsigned int p1 = f2bf(src[2]) | ((unsigned int)f2bf(src[3]) << 16);
        unsigned int p2 = f2bf(src[4]) | ((unsigned int)f2bf(src[5]) << 16);
        unsigned int p3 = f2bf(src[6]) | ((unsigned int)f2bf(src[7]) << 16);
        *(uint4*)(Bs + (size_t)idx * 8) = make_uint4(p0, p1, p2, p3);
    } else if (blk < 224) {
        int b = blk - 160;
        if (tid < EE) sh[tid] = emb_W[(size_t)z_tm1[b] * EE + tid];
        __syncthreads();
        if (tid < EE) {
            const float4* wrow = (const float4*)(ctrl_W + (size_t)tid * EE);
            float a0 = 0.f, a1 = 0.f;
            for (int k4 = 0; k4 < EE / 4; k4 += 2) {
                float4 w0 = wrow[k4], w1 = wrow[k4 + 1];
                a0 += sh[k4*4+0]*w0.x + sh[k4*4+1]*w0.y + sh[k4*4+2]*w0.z + sh[k4*4+3]*w0.w;
                a1 += sh[k4*4+4]*w1.x + sh[k4*4+5]*w1.y + sh[k4*4+6]*w1.z + sh[k4*4+7]*w1.w;
            }
            embed[b * EE + tid] = ctrl_b[tid] + sh[tid] + a0 + a1;
        }
        __syncthreads();
    } else if (blk < 232) {
        int lblk = (blk - 224) * 2;
        shi[tid] = slot[lblk * SS + tid];
        __syncthreads();
        int lrow = tid >> 7, s = tid & 127;
        int c = shi[lrow * 128 + s];
        int fi = s;
        for (int s2 = 0; s2 < 128; ++s2) {
            if (shi[lrow * 128 + s2] == c) { fi = s2; break; }
        }
        fidx[(lblk + lrow) * SS + s] = fi;
        __syncthreads();
    }
}

__device__ __forceinline__ void sctx_phase(int c, int b, int tid,
                                           const float* __restrict__ enc,
                                           const unsigned short* __restrict__ Bs,
                                           const float* __restrict__ attn_v,
                                           const float* __restrict__ hWp,
                                           float* __restrict__ partial,
                                           float* __restrict__ mArr,
                                           float* __restrict__ dArr,
                                           float* smem) {
    unsigned char* Abuf = (unsigned char*)smem;       // 4096 f
    float* scpart = smem + 4096;                      // 128
    float* wloc   = smem + 4224;                      // 32
    float* part   = smem + 4256;                      // 1024
    int t0 = c * 32;

#pragma unroll
    for (int it = 0; it < 4; ++it) {
        int ci = tid + it * 256;
        int row = ci >> 5;
        int kc = ci & 31;
        const float* src = enc + ((size_t)(t0 + row) * BB + b) * HH + kc * 8;
        float4 f0 = *(const float4*)src;
        float4 f1 = *(const float4*)(src + 4);
        unsigned int p0 = f2bf(f0.x) | ((unsigned int)f2bf(f0.y) << 16);
        unsigned int p1 = f2bf(f0.z) | ((unsigned int)f2bf(f0.w) << 16);
        unsigned int p2 = f2bf(f1.x) | ((unsigned int)f2bf(f1.y) << 16);
        unsigned int p3 = f2bf(f1.z) | ((unsigned int)f2bf(f1.w) << 16);
        int addr = (row * 512 + kc * 16) ^ ((row & 7) << 4);
        *(uint4*)(Abuf + addr) = make_uint4(p0, p1, p2, p3);
    }
    __syncthreads();

    int wv = tid >> 6, lane = tid & 63;
    int lrow = lane & 15, q = lane >> 4;

    f32x4 acc[2][4];
#pragma unroll
    for (int rt = 0; rt < 2; ++rt)
#pragma unroll
        for (int ct = 0; ct < 4; ++ct) acc[rt][ct] = (f32x4){0.f, 0.f, 0.f, 0.f};

    const bf16x8* BsV = (const bf16x8*)Bs;
    for (int ks = 0; ks < 8; ++ks) {
        bf16x8 bfr[4];
        const bf16x8* bsrc = BsV + ((size_t)(ks * 16 + wv * 4) * 64 + lane);
#pragma unroll
        for (int ct = 0; ct < 4; ++ct) bfr[ct] = bsrc[ct * 64];
        bf16x8 afr[2];
#pragma unroll
        for (int rt = 0; rt < 2; ++rt) {
            int arow = rt * 16 + lrow;
            int abyte = (arow * 512 + ks * 64 + q * 16) ^ ((arow & 7) << 4);
            afr[rt] = *(const bf16x8*)(Abuf + abyte);
        }
#pragma unroll
        for (int rt = 0; rt < 2; ++rt)
#pragma unroll
            for (int ct = 0; ct < 4; ++ct)
                acc[rt][ct] = __builtin_amdgcn_mfma_f32_16x16x32_bf16(afr[rt], bfr[ct], acc[rt][ct], 0, 0, 0);
    }

    float vvv[4], hwv[4];
#pragma unroll
    for (int ct = 0; ct < 4; ++ct) {
        int col = wv * 64 + ct * 16 + lrow;
        vvv[ct] = attn_v[col];
        hwv[ct] = hWp[(size_t)b * HH + col] + hWp[16384 + (size_t)b * HH + col];
    }
#pragma unroll
    for (int rt = 0; rt < 2; ++rt) {
        float ps[4];
#pragma unroll
        for (int r = 0; r < 4; ++r) {
            float s = 0.f;
#pragma unroll
            for (int ct = 0; ct < 4; ++ct)
                s += vvv[ct] * ftanh(acc[rt][ct][r] + hwv[ct]);
#pragma unroll
            for (int off = 1; off < 16; off <<= 1) s += __shfl_xor(s, off, 64);
            ps[r] = s;
        }
        if (lrow == 0) {
#pragma unroll
            for (int r = 0; r < 4; ++r) scpart[wv * 32 + rt * 16 + q * 4 + r] = ps[r];
        }
    }
    __syncthreads();

    if (tid < 64) {
        float s = (tid < 32)
            ? ((scpart[tid] + scpart[32 + tid]) + (scpart[64 + tid] + scpart[96 + tid]))
            : -3.0e38f;
        float mx = s;
#pragma unroll
        for (int off = 32; off; off >>= 1) mx = fmaxf(mx, __shfl_xor(mx, off, 64));
        float e = (tid < 32) ? expf(s - mx) : 0.f;
        float d = e;
#pragma unroll
        for (int off = 32; off; off >>= 1) d += __shfl_xor(d, off, 64);
        if (tid < 32) wloc[tid] = e;
        if (tid == 0) { mArr[b * 16 + c] = mx; dArr[b * 16 + c] = d; }
    }
    __syncthreads();

    {
        int h4 = tid & 63, g = tid >> 6;
        float c0 = 0.f, c1 = 0.f, c2 = 0.f, c3 = 0.f;
#pragma unroll
        for (int i = 0; i < 8; ++i) {
            int row = g * 8 + i;
            float wt = wloc[row];
            int baddr = ((row * 512 + (h4 >> 1) * 16) ^ ((row & 7) << 4)) + (h4 & 1) * 8;
            ushort4 u = *(const ushort4*)(Abuf + baddr);
            c0 += wt * __uint_as_float((unsigned int)u.x << 16);
            c1 += wt * __uint_as_float((unsigned int)u.y << 16);
            c2 += wt * __uint_as_float((unsigned int)u.z << 16);
            c3 += wt * __uint_as_float((unsigned int)u.w << 16);
        }
        part[g * 256 + h4 * 4 + 0] = c0;
        part[g * 256 + h4 * 4 + 1] = c1;
        part[g * 256 + h4 * 4 + 2] = c2;
        part[g * 256 + h4 * 4 + 3] = c3;
    }
    __syncthreads();
    if (tid < 64) {
        f32x4 a0 = *(const f32x4*)&part[0 * 256 + tid * 4];
        f32x4 a1 = *(const f32x4*)&part[1 * 256 + tid * 4];
        f32x4 a2 = *(const f32x4*)&part[2 * 256 + tid * 4];
        f32x4 a3 = *(const f32x4*)&part[3 * 256 + tid * 4];
        f32x4 t4;
        t4.x = (a0.x + a1.x) + (a2.x + a3.x);
        t4.y = (a0.y + a1.y) + (a2.y + a3.y);
        t4.z = (a0.z + a1.z) + (a2.z + a3.z);
        t4.w = (a0.w + a1.w) + (a2.w + a3.w);
        *(f32x4*)&partial[((size_t)b * 16 + c) * HH + tid * 4] = t4;  // [b][c][h]
    }
    __syncthreads();
}

__device__ __forceinline__ void fin_phase(int bx, int tid,
                                          const float* __restrict__ partial,
                                          const float* __restrict__ mArr,
                                          const float* __restrict__ dArr,
                                          const float* __restrict__ embed,
                                          const float* __restrict__ last_hidden,
                                          float* __restrict__ fin,
                                          float* smem) {
    float* ldm = smem;
    float* ldd = smem + 16;
    int b = bx >> 2, qq = bx & 3;
    if (tid < 16) { ldm[tid] = mArr[b * 16 + tid]; ldd[tid] = dArr[b * 16 + tid]; }
    __syncthreads();
    float M = ldm[0];
#pragma unroll
    for (int c = 1; c < 16; ++c) M = fmaxf(M, ldm[c]);
    float den = 0.f;
#pragma unroll
    for (int c = 0; c < 16; ++c) den += expf(ldm[c] - M) * ldd[c];
    float invden = 1.f / den;

    int j = qq * 160 + tid;
    if (tid < 160) {
        float v;
        if (j < EE) v = embed[b * EE + j];
        else if (j < EE + HH) {
            int h = j - EE;
            const float* pb = partial + (size_t)b * 16 * HH + h;
            float a0 = 0.f, a1 = 0.f;
#pragma unroll
            for (int c = 0; c < 16; c += 2) {
                a0 += expf(ldm[c] - M) * pb[(size_t)c * HH];
                a1 += expf(ldm[c + 1] - M) * pb[(size_t)(c + 1) * HH];
            }
            v = (a0 + a1) * invden;
        } else v = last_hidden[b * HH + (j - EE - HH)];
        fin[b * 640 + j] = v;
    }
    __syncthreads();
}

__device__ __forceinline__ void hid_phase(int bx, int tid,
                                          const float* __restrict__ fin,
                                          const float* __restrict__ Whid,
                                          float* __restrict__ paccum,
                                          float* smem) {
    float* W_sl = smem;            // 640
    float* fin_sl = smem + 640;    // 5184
    int og = bx >> 3, kg = bx & 7;
    int k0 = kg * 80, o0 = og * 8;

    for (int i = tid; i < 8 * 80; i += 256) {
        int o = i / 80, kk = i - o * 80;
        W_sl[i] = Whid[(size_t)(o0 + o) * 640 + k0 + kk];
    }
    {
        int b = tid & 63, kc = tid >> 6;
#pragma unroll
        for (int j = 0; j < 20; ++j) {
            int kk = kc * 20 + j;
            fin_sl[b * 81 + kk] = fin[b * 640 + k0 + kk];
        }
    }
    __syncthreads();

    int b = tid & 63, g = tid >> 6;
    float a0 = 0.f, a1 = 0.f;
    for (int kk = 0; kk < 80; kk += 4) {
        f32x4 w0 = *(const f32x4*)&W_sl[(g * 2) * 80 + kk];
        f32x4 w1 = *(const f32x4*)&W_sl[(g * 2 + 1) * 80 + kk];
        float f0 = fin_sl[b * 81 + kk + 0];
        float f1 = fin_sl[b * 81 + kk + 1];
        float f2 = fin_sl[b * 81 + kk + 2];
        float f3 = fin_sl[b * 81 + kk + 3];
        a0 += f0 * w0.x + f1 * w0.y + f2 * w0.z + f3 * w0.w;
        a1 += f0 * w1.x + f1 * w1.y + f2 * w1.z + f3 * w1.w;
    }
    paccum[kg * 16384 + b * 256 + o0 + g * 2 + 0] = a0;
    paccum[kg * 16384 + b * 256 + o0 + g * 2 + 1] = a1;
    __syncthreads();
}

__device__ __forceinline__ void gensum_phase(int bx, int tid,
                                             const float* __restrict__ paccum,
                                             const float* __restrict__ bhid,
                                             const float* __restrict__ Wout,
                                             const float* __restrict__ bout,
                                             float* __restrict__ out_hidden,
                                             float* __restrict__ gen,
                                             float* smem) {
    float* WoutL = smem;            // 1024
    float* hid_ld = smem + 1024;    // 2056
    float* boutL = smem + 3080;     // 4
    int sg = bx >> 3, bh = bx & 7;
    int b0 = bh * 8;

    for (int i = tid; i < 4 * 256; i += 256)
        WoutL[i] = Wout[(size_t)(sg * 4 + (i >> 8)) * HH + (i & 255)];
    if (tid < 4) boutL[tid] = bout[sg * 4 + tid];

#pragma unroll
    for (int it = 0; it < 8; ++it) {
        int bidx = (b0 + it) * 256 + tid;
        float v = ((paccum[0 * 16384 + bidx] + paccum[1 * 16384 + bidx])
                 + (paccum[2 * 16384 + bidx] + paccum[3 * 16384 + bidx]))
                + ((paccum[4 * 16384 + bidx] + paccum[5 * 16384 + bidx])
                 + (paccum[6 * 16384 + bidx] + paccum[7 * 16384 + bidx]))
                + bhid[tid];
        hid_ld[it * 257 + tid] = fmaxf(v, 0.f);
    }
    __syncthreads();

    if (sg == 0) {
#pragma unroll
        for (int it = 0; it < 8; ++it)
            out_hidden[(size_t)(b0 + it) * HH + tid] = hid_ld[it * 257 + tid];
    }

    {
        int oi = tid >> 3, kt = tid & 7;
        int sq = oi >> 3, bq = oi & 7;
        float acc = 0.f;
#pragma unroll 8
        for (int jj = 0; jj < 32; ++jj) {
            int k = kt * 32 + ((jj + 4 * kt) & 31);
            acc += hid_ld[bq * 257 + k] * WoutL[sq * 256 + k];
        }
        acc += __shfl_xor(acc, 1, 64);
        acc += __shfl_xor(acc, 2, 64);
        acc += __shfl_xor(acc, 4, 64);
        if (kt == 0)
            gen[(size_t)(b0 + bq) * SS + sg * 4 + sq] = fmaxf(acc + boutL[sq], 0.f);
    }
    __syncthreads();
}

__device__ __forceinline__ void fill_phase(int bx, int tid,
                                           const int* __restrict__ slot,
                                           const int* __restrict__ fidx,
                                           const float* __restrict__ gen,
                                           float* __restrict__ out,
                                           float* smem) {
    float* genl = smem;             // 128
    float* genacc = smem + 128;     // 128
    float* pv = smem + 256;         // 128
    float* red = smem + 384;        // 12
    int* fidxL = (int*)(smem + 396);  // 128
    int* cls = (int*)(smem + 524);    // 128
    int l = bx >> 6, b = bx & 63;
    int lane = tid & 63, wv = tid >> 6;

    if (tid < SS) {
        genl[tid] = gen[(size_t)b * SS + tid];
        fidxL[tid] = fidx[l * SS + tid];
        cls[tid] = slot[l * SS + tid];
        genacc[tid] = 0.f;
    }
    __syncthreads();
    if (tid < SS) atomicAdd(&genacc[fidxL[tid]], genl[tid]);
    __syncthreads();

    float mg = 0.f;
    bool first = false;
    if (tid < SS) {
        first = (fidxL[tid] == tid);
        mg = -0.01f + genacc[tid];
    }
    float mx = first ? mg : -3.0e38f;
#pragma unroll
    for (int off = 32; off; off >>= 1) mx = fmaxf(mx, __shfl_xor(mx, off, 64));
    if (lane == 0) red[wv] = mx;
    __syncthreads();
    float M = fmaxf(red[0], red[1]);
    float e = first ? expf(mg - M) : 0.f;
    float s1 = e, s2 = first ? 1.f : 0.f;
#pragma unroll
    for (int off = 32; off; off >>= 1) {
        s1 += __shfl_xor(s1, off, 64);
        s2 += __shfl_xor(s2, off, 64);
    }
    if (lane == 0) { red[4 + wv] = s1; red[8 + wv] = s2; }
    __syncthreads();
    float sumHits = red[4] + red[5];
    float cntv = red[8] + red[9];
    float base = expf(-0.01f - M);
    float inv = 1.f / (((float)VV - cntv) * base + sumHits);
    float pb = base * inv;
    if (tid < SS) pv[tid] = first ? e * inv : -1.f;
    __syncthreads();

    float* rowp = out + BB * HH + ((size_t)(l * BB + b)) * VV;
    float4 p4 = make_float4(pb, pb, pb, pb);
    float4* row4 = (float4*)rowp;
#pragma unroll 4
    for (int idx = tid; idx < VV / 4; idx += 256) row4[idx] = p4;
    __syncthreads();
    if (tid < SS && pv[tid] >= 0.f) rowp[cls[tid]] = pv[tid];
}

// ---------------- cooperative mega-kernel ----------------
__global__ __launch_bounds__(256, 4) void k_mega(const float* __restrict__ enc,
                                                 const float* __restrict__ last_hidden,
                                                 const int* __restrict__ z_tm1,
                                                 const int* __restrict__ slot,
                                                 const float* __restrict__ emb_W,
                                                 const float* __restrict__ ctrl_W,
                                                 const float* __restrict__ ctrl_b,
                                                 const float* __restrict__ attn_W,
                                                 const float* __restrict__ attn_b,
                                                 const float* __restrict__ attn_v,
                                                 const float* __restrict__ Whid,
                                                 const float* __restrict__ bhid,
                                                 const float* __restrict__ Wout,
                                                 const float* __restrict__ bout,
                                                 float* __restrict__ out,
                                                 float* __restrict__ hWp,
                                                 float* __restrict__ embed,
                                                 float* __restrict__ gen,
                                                 unsigned short* __restrict__ Bs,
                                                 float* __restrict__ partial,
                                                 float* __restrict__ fin,
                                                 float* __restrict__ paccum,
                                                 int* __restrict__ fidx,
                                                 float* __restrict__ mArr,
                                                 float* __restrict__ dArr) {
    cg::grid_group grid = cg::this_grid();
    __shared__ __align__(16) float smem[5856];
    int bid = blockIdx.x;
    int tid = threadIdx.x;

    if (bid < 232)
        pre_phase(bid, tid, last_hidden, attn_W, attn_b, z_tm1, emb_W, ctrl_W, ctrl_b,
                  slot, hWp, embed, Bs, fidx, smem);
    grid.sync();
    sctx_phase(bid & 15, bid >> 4, tid, enc, Bs, attn_v, hWp, partial, mArr, dArr, smem);
    grid.sync();
    if (bid < 256)
        fin_phase(bid, tid, partial, mArr, dArr, embed, last_hidden, fin, smem);
    grid.sync();
    if (bid < 256)
        hid_phase(bid, tid, fin, Whid, paccum, smem);
    grid.sync();
    if (bid < 256)
        gensum_phase(bid, tid, paccum, bhid, Wout, bout, out, gen, smem);
    grid.sync();
    fill_phase(bid, tid, slot, fidx, gen, out, smem);
}

// ---------------- fallback standalone kernels (same bodies) ----------------
__global__ __launch_bounds__(256) void k_pre(const float* __restrict__ last_hidden,
                                             const float* __restrict__ attn_W,
                                             const float* __restrict__ attn_b,
                                             const int* __restrict__ z_tm1,
                                             const float* __restrict__ emb_W,
                                             const float* __restrict__ ctrl_W,
                                             const float* __restrict__ ctrl_b,
                                             const int* __restrict__ slot,
                                             float* __restrict__ hWp,
                                             float* __restrict__ embed,
                                             unsigned short* __restrict__ Bs,
                                             int* __restrict__ fidx) {
    __shared__ __align__(16) float smem[512];
    pre_phase(blockIdx.x, threadIdx.x, last_hidden, attn_W, attn_b, z_tm1, emb_W,
              ctrl_W, ctrl_b, slot, hWp, embed, Bs, fidx, smem);
}

__global__ __launch_bounds__(256) void k_sctx(const float* __restrict__ enc,
                                              const unsigned short* __restrict__ Bs,
                                              const float* __restrict__ attn_v,
                                              const float* __restrict__ hWp,
                                              float* __restrict__ partial,
                                              float* __restrict__ mArr,
                                              float* __restrict__ dArr) {
    __shared__ __align__(16) float smem[5280];
    sctx_phase(blockIdx.x, blockIdx.y, threadIdx.x, enc, Bs, attn_v, hWp,
               partial, mArr, dArr, smem);
}

__global__ __launch_bounds__(256) void k_fin(const float* __restrict__ partial,
                                             const float* __restrict__ mArr,
                                             const float* __restrict__ dArr,
                                             const float* __restrict__ embed,
                                             const float* __restrict__ last_hidden,
                                             float* __restrict__ fin) {
    __shared__ __align__(16) float smem[32];
    fin_phase(blockIdx.x, threadIdx.x, partial, mArr, dArr, embed, last_hidden, fin, smem);
}

__global__ __launch_bounds__(256) void k_hid(const float* __restrict__ fin,
                                             const float* __restrict__ Whid,
                                             float* __restrict__ paccum) {
    __shared__ __align__(16) float smem[5824];
    hid_phase(blockIdx.x, threadIdx.x, fin, Whid, paccum, smem);
}

__global__ __launch_bounds__(256) void k_gensum(const float* __restrict__ paccum,
                                                const float* __restrict__ bhid,
                                                const float* __restrict__ Wout,
                                                const float* __restrict__ bout,
                                                float* __restrict__ out_hidden,
                                                float* __restrict__ gen) {
    __shared__ __align__(16) float smem[3084];
    gensum_phase(blockIdx.x, threadIdx.x, paccum, bhid, Wout, bout, out_hidden, gen, smem);
}

__global__ __launch_bounds__(256) void k_fill(const int* __restrict__ slot,
                                              const int* __restrict__ fidx,
                                              const float* __restrict__ gen,
                                              float* __restrict__ out) {
    __shared__ __align__(16) float smem[656];
    fill_phase(blockIdx.x, threadIdx.x, slot, fidx, gen, out, smem);
}

extern "C" void kernel_launch(void* const* d_in, const int* in_sizes, int n_in,
                              void* d_out, int out_size, void* d_ws, size_t ws_size,
                              hipStream_t stream) {
    const float* u_enc       = (const float*)d_in[0];
    const float* last_hidden = (const float*)d_in[1];
    const int*   z_tm1       = (const int*)d_in[2];
    const int*   slot        = (const int*)d_in[3];
    const float* emb_W       = (const float*)d_in[4];
    const float* ctrl_W      = (const float*)d_in[5];
    const float* ctrl_b      = (const float*)d_in[6];
    const float* attn_W      = (const float*)d_in[7];
    const float* attn_b      = (const float*)d_in[8];
    const float* attn_v      = (const float*)d_in[9];
    const float* Whid        = (const float*)d_in[10];
    const float* bhid        = (const float*)d_in[11];
    const float* Wout        = (const float*)d_in[12];
    const float* bout        = (const float*)d_in[13];
    float* out = (float*)d_out;
    float* ws = (float*)d_ws;

    float* mArr    = ws;              // 1024
    float* dArr    = ws + 1024;       // 1024
    float* hWp     = ws + 2048;       // 32768
    float* embed   = ws + 34816;      // 8192
    float* gen     = ws + 43008;      // 8192
    unsigned short* Bs = (unsigned short*)(ws + 51200);  // 65536 bf16
    float* partial = ws + 83968;      // 262144  ([b][c][h])
    float* fin     = ws + 346112;     // 40960
    float* paccum  = ws + 387072;     // 131072
    int*   fidx    = (int*)(ws + 518144);  // 2048 ints

    void* args[] = {
        (void*)&u_enc, (void*)&last_hidden, (void*)&z_tm1, (void*)&slot,
        (void*)&emb_W, (void*)&ctrl_W, (void*)&ctrl_b, (void*)&attn_W,
        (void*)&attn_b, (void*)&attn_v, (void*)&Whid, (void*)&bhid,
        (void*)&Wout, (void*)&bout, (void*)&out, (void*)&hWp, (void*)&embed,
        (void*)&gen, (void*)&Bs, (void*)&partial, (void*)&fin, (void*)&paccum,
        (void*)&fidx, (void*)&mArr, (void*)&dArr
    };
    hipError_t err = hipLaunchCooperativeKernel((void*)k_mega, dim3(1024), dim3(256),
                                                args, 0, stream);
    if (err != hipSuccess) {
        // fallback: identical 6-kernel pipeline (deterministic per-context)
        k_pre<<<232, 256, 0, stream>>>(last_hidden, attn_W, attn_b, z_tm1, emb_W,
                                       ctrl_W, ctrl_b, slot, hWp, embed, Bs, fidx);
        dim3 gs(16, BB);
        k_sctx<<<gs, 256, 0, stream>>>(u_enc, Bs, attn_v, hWp, partial, mArr, dArr);
        k_fin<<<BB * 4, 256, 0, stream>>>(partial, mArr, dArr, embed, last_hidden, fin);
        k_hid<<<256, 256, 0, stream>>>(fin, Whid, paccum);
        k_gensum<<<256, 256, 0, stream>>>(paccum, bhid, Wout, bout, out, gen);
        k_fill<<<LL * BB, 256, 0, stream>>>(slot, fidx, gen, out);
    }
}

// Round 22
// 64.143 us; speedup vs baseline: 9.3127x; 9.3127x over previous
//
#include <hip/hip_runtime.h>
#include <hip/hip_bf16.h>

#define BB 64
#define TT 512
#define HH 256
#define EE 128
#define VV 32000
#define SS 128
#define LL 16

typedef __attribute__((ext_vector_type(8))) short bf16x8;
typedef __attribute__((ext_vector_type(4))) float f32x4;

static __device__ __forceinline__ unsigned short f2bf(float x) {
    unsigned int u = __float_as_uint(x);
    unsigned int r = (u + 0x7fffu + ((u >> 16) & 1u)) >> 16;
    return (unsigned short)r;
}

// tanh(x) = 1 - 2/(exp2(x*2*log2e)+1)
static __device__ __forceinline__ float ftanh(float x) {
    float y = __builtin_amdgcn_exp2f(x * 2.885390082f);
    return 1.f - 2.f * __builtin_amdgcn_rcpf(y + 1.f);
}

// ================= K1: {hW split-k, prep_b, embed, fidx}, 232 blocks =================
__global__ __launch_bounds__(256) void k_pre(const float* __restrict__ last_hidden,
                                             const float* __restrict__ attn_W,
                                             const float* __restrict__ attn_b,
                                             const int* __restrict__ z_tm1,
                                             const float* __restrict__ emb_W,
                                             const float* __restrict__ ctrl_W,
                                             const float* __restrict__ ctrl_b,
                                             const int* __restrict__ slot,
                                             float* __restrict__ hWp,
                                             float* __restrict__ embed,
                                             unsigned short* __restrict__ Bs,
                                             int* __restrict__ fidx) {
    __shared__ float sh[HH];
    __shared__ int shi[256];
    int blk = blockIdx.x;
    int tid = threadIdx.x;
    if (blk < 128) {
        int b = blk >> 1, kh = blk & 1;
        if (tid < 128) sh[tid] = last_hidden[b * HH + kh * 128 + tid];
        __syncthreads();
        const float4* wrow = (const float4*)(attn_W + (size_t)tid * (2 * HH) + kh * 128);
        float a0 = 0.f, a1 = 0.f;
        for (int k4 = 0; k4 < 32; k4 += 2) {
            float4 w0 = wrow[k4], w1 = wrow[k4 + 1];
            a0 += sh[k4*4+0]*w0.x + sh[k4*4+1]*w0.y + sh[k4*4+2]*w0.z + sh[k4*4+3]*w0.w;
            a1 += sh[k4*4+4]*w1.x + sh[k4*4+5]*w1.y + sh[k4*4+6]*w1.z + sh[k4*4+7]*w1.w;
        }
        float r = a0 + a1;
        if (kh == 0) r += attn_b[tid];
        hWp[kh * 16384 + b * 256 + tid] = r;
    } else if (blk < 160) {
        int idx = (blk - 128) * 256 + tid;  // 8192 total
        int lane = idx & 63;
        int gt = (idx >> 6) & 15;
        int ks = idx >> 10;
        int col = gt * 16 + (lane & 15);
        int k0 = ks * 32 + (lane >> 4) * 8;
        const float* src = attn_W + (size_t)col * (2 * HH) + HH + k0;
        unsigned int p0 = f2bf(src[0]) | ((unsigned int)f2bf(src[1]) << 16);
        unsigned int p1 = f2bf(src[2]) | ((unsigned int)f2bf(src[3]) << 16);
        unsigned int p2 = f2bf(src[4]) | ((unsigned int)f2bf(src[5]) << 16);
        unsigned int p3 = f2bf(src[6]) | ((unsigned int)f2bf(src[7]) << 16);
        *(uint4*)(Bs + (size_t)idx * 8) = make_uint4(p0, p1, p2, p3);
    } else if (blk < 224) {
        int b = blk - 160;
        if (tid < EE) sh[tid] = emb_W[(size_t)z_tm1[b] * EE + tid];
        __syncthreads();
        if (tid < EE) {
            const float4* wrow = (const float4*)(ctrl_W + (size_t)tid * EE);
            float a0 = 0.f, a1 = 0.f;
            for (int k4 = 0; k4 < EE / 4; k4 += 2) {
                float4 w0 = wrow[k4], w1 = wrow[k4 + 1];
                a0 += sh[k4*4+0]*w0.x + sh[k4*4+1]*w0.y + sh[k4*4+2]*w0.z + sh[k4*4+3]*w0.w;
                a1 += sh[k4*4+4]*w1.x + sh[k4*4+5]*w1.y + sh[k4*4+6]*w1.z + sh[k4*4+7]*w1.w;
            }
            embed[b * EE + tid] = ctrl_b[tid] + sh[tid] + a0 + a1;
        }
    } else {
        int lblk = (blk - 224) * 2;
        shi[tid] = slot[lblk * SS + tid];
        __syncthreads();
        int lrow = tid >> 7, s = tid & 127;
        int c = shi[lrow * 128 + s];
        int fi = s;
        for (int s2 = 0; s2 < 128; ++s2) {
            if (shi[lrow * 128 + s2] == c) { fi = s2; break; }
        }
        fidx[(lblk + lrow) * SS + s] = fi;
    }
}

// ================= K2: fused scores+context (flash-style), block=(c,b) =================
__global__ __launch_bounds__(256) void k_sctx(const float* __restrict__ enc,
                                              const unsigned short* __restrict__ Bs,
                                              const float* __restrict__ attn_v,
                                              const float* __restrict__ hWp,
                                              float* __restrict__ partial,
                                              float* __restrict__ mArr,
                                              float* __restrict__ dArr) {
    __shared__ uint4 AbufV[1024];
    __shared__ float scpart[128];
    __shared__ float wloc[32];
    __shared__ __align__(16) float part[1024];
    unsigned char* Abuf = (unsigned char*)AbufV;

    int c = blockIdx.x, b = blockIdx.y;
    int tid = threadIdx.x;
    int t0 = c * 32;

#pragma unroll
    for (int it = 0; it < 4; ++it) {
        int ci = tid + it * 256;
        int row = ci >> 5;
        int kc = ci & 31;
        const float* src = enc + ((size_t)(t0 + row) * BB + b) * HH + kc * 8;
        float4 f0 = *(const float4*)src;
        float4 f1 = *(const float4*)(src + 4);
        unsigned int p0 = f2bf(f0.x) | ((unsigned int)f2bf(f0.y) << 16);
        unsigned int p1 = f2bf(f0.z) | ((unsigned int)f2bf(f0.w) << 16);
        unsigned int p2 = f2bf(f1.x) | ((unsigned int)f2bf(f1.y) << 16);
        unsigned int p3 = f2bf(f1.z) | ((unsigned int)f2bf(f1.w) << 16);
        int addr = (row * 512 + kc * 16) ^ ((row & 7) << 4);
        *(uint4*)(Abuf + addr) = make_uint4(p0, p1, p2, p3);
    }
    __syncthreads();

    int wv = tid >> 6, lane = tid & 63;
    int lrow = lane & 15, q = lane >> 4;

    f32x4 acc[2][4];
#pragma unroll
    for (int rt = 0; rt < 2; ++rt)
#pragma unroll
        for (int ct = 0; ct < 4; ++ct) acc[rt][ct] = (f32x4){0.f, 0.f, 0.f, 0.f};

    const bf16x8* BsV = (const bf16x8*)Bs;
    for (int ks = 0; ks < 8; ++ks) {
        bf16x8 bfr[4];
        const bf16x8* bsrc = BsV + ((size_t)(ks * 16 + wv * 4) * 64 + lane);
#pragma unroll
        for (int ct = 0; ct < 4; ++ct) bfr[ct] = bsrc[ct * 64];
        bf16x8 afr[2];
#pragma unroll
        for (int rt = 0; rt < 2; ++rt) {
            int arow = rt * 16 + lrow;
            int abyte = (arow * 512 + ks * 64 + q * 16) ^ ((arow & 7) << 4);
            afr[rt] = *(const bf16x8*)(Abuf + abyte);
        }
#pragma unroll
        for (int rt = 0; rt < 2; ++rt)
#pragma unroll
            for (int ct = 0; ct < 4; ++ct)
                acc[rt][ct] = __builtin_amdgcn_mfma_f32_16x16x32_bf16(afr[rt], bfr[ct], acc[rt][ct], 0, 0, 0);
    }

    float vvv[4], hwv[4];
#pragma unroll
    for (int ct = 0; ct < 4; ++ct) {
        int col = wv * 64 + ct * 16 + lrow;
        vvv[ct] = attn_v[col];
        hwv[ct] = hWp[(size_t)b * HH + col] + hWp[16384 + (size_t)b * HH + col];
    }
#pragma unroll
    for (int rt = 0; rt < 2; ++rt) {
        float ps[4];
#pragma unroll
        for (int r = 0; r < 4; ++r) {
            float s = 0.f;
#pragma unroll
            for (int ct = 0; ct < 4; ++ct)
                s += vvv[ct] * ftanh(acc[rt][ct][r] + hwv[ct]);
#pragma unroll
            for (int off = 1; off < 16; off <<= 1) s += __shfl_xor(s, off, 64);
            ps[r] = s;
        }
        if (lrow == 0) {
#pragma unroll
            for (int r = 0; r < 4; ++r) scpart[wv * 32 + rt * 16 + q * 4 + r] = ps[r];
        }
    }
    __syncthreads();

    if (tid < 64) {
        float s = (tid < 32)
            ? ((scpart[tid] + scpart[32 + tid]) + (scpart[64 + tid] + scpart[96 + tid]))
            : -3.0e38f;
        float mx = s;
#pragma unroll
        for (int off = 32; off; off >>= 1) mx = fmaxf(mx, __shfl_xor(mx, off, 64));
        float e = (tid < 32) ? expf(s - mx) : 0.f;
        float d = e;
#pragma unroll
        for (int off = 32; off; off >>= 1) d += __shfl_xor(d, off, 64);
        if (tid < 32) wloc[tid] = e;
        if (tid == 0) { mArr[b * 16 + c] = mx; dArr[b * 16 + c] = d; }
    }
    __syncthreads();

    {
        int h4 = tid & 63, g = tid >> 6;
        float c0 = 0.f, c1 = 0.f, c2 = 0.f, c3 = 0.f;
#pragma unroll
        for (int i = 0; i < 8; ++i) {
            int row = g * 8 + i;
            float wt = wloc[row];
            int baddr = ((row * 512 + (h4 >> 1) * 16) ^ ((row & 7) << 4)) + (h4 & 1) * 8;
            ushort4 u = *(const ushort4*)(Abuf + baddr);
            c0 += wt * __uint_as_float((unsigned int)u.x << 16);
            c1 += wt * __uint_as_float((unsigned int)u.y << 16);
            c2 += wt * __uint_as_float((unsigned int)u.z << 16);
            c3 += wt * __uint_as_float((unsigned int)u.w << 16);
        }
        part[g * 256 + h4 * 4 + 0] = c0;
        part[g * 256 + h4 * 4 + 1] = c1;
        part[g * 256 + h4 * 4 + 2] = c2;
        part[g * 256 + h4 * 4 + 3] = c3;
    }
    __syncthreads();
    if (tid < 64) {
        f32x4 a0 = *(const f32x4*)&part[0 * 256 + tid * 4];
        f32x4 a1 = *(const f32x4*)&part[1 * 256 + tid * 4];
        f32x4 a2 = *(const f32x4*)&part[2 * 256 + tid * 4];
        f32x4 a3 = *(const f32x4*)&part[3 * 256 + tid * 4];
        f32x4 t4;
        t4.x = (a0.x + a1.x) + (a2.x + a3.x);
        t4.y = (a0.y + a1.y) + (a2.y + a3.y);
        t4.z = (a0.z + a1.z) + (a2.z + a3.z);
        t4.w = (a0.w + a1.w) + (a2.w + a3.w);
        *(f32x4*)&partial[((size_t)b * 16 + c) * HH + tid * 4] = t4;  // [b][c][h]
    }
}

// ================= K3: fin[b][640], 256 blocks (b x quarter), coalesced =================
__global__ __launch_bounds__(256) void k_fin(const float* __restrict__ partial,
                                             const float* __restrict__ mArr,
                                             const float* __restrict__ dArr,
                                             const float* __restrict__ embed,
                                             const float* __restrict__ last_hidden,
                                             float* __restrict__ fin) {
    __shared__ float ldm[16], ldd[16];
    int b = blockIdx.x >> 2, qq = blockIdx.x & 3;
    int tid = threadIdx.x;
    if (tid < 16) { ldm[tid] = mArr[b * 16 + tid]; ldd[tid] = dArr[b * 16 + tid]; }
    __syncthreads();
    float M = ldm[0];
#pragma unroll
    for (int c = 1; c < 16; ++c) M = fmaxf(M, ldm[c]);
    float den = 0.f;
#pragma unroll
    for (int c = 0; c < 16; ++c) den += expf(ldm[c] - M) * ldd[c];
    float invden = 1.f / den;

    int j = qq * 160 + tid;
    if (tid < 160) {
        float v;
        if (j < EE) v = embed[b * EE + j];
        else if (j < EE + HH) {
            int h = j - EE;
            const float* pb = partial + (size_t)b * 16 * HH + h;
            float a0 = 0.f, a1 = 0.f;
#pragma unroll
            for (int c = 0; c < 16; c += 2) {
                a0 += expf(ldm[c] - M) * pb[(size_t)c * HH];
                a1 += expf(ldm[c + 1] - M) * pb[(size_t)(c + 1) * HH];
            }
            v = (a0 + a1) * invden;
        } else v = last_hidden[b * HH + (j - EE - HH)];
        fin[b * 640 + j] = v;
    }
}

// ================= K4: hidden partial GEMM, 256 blocks (og 32 x kg 8) =================
__global__ __launch_bounds__(256) void k_hid(const float* __restrict__ fin,
                                             const float* __restrict__ Whid,
                                             float* __restrict__ paccum) {
    __shared__ __align__(16) float W_sl[8 * 80];
    __shared__ float fin_sl[64 * 81];
    int og = blockIdx.x >> 3, kg = blockIdx.x & 7;
    int tid = threadIdx.x;
    int k0 = kg * 80, o0 = og * 8;

    for (int i = tid; i < 8 * 80; i += 256) {
        int o = i / 80, kk = i - o * 80;
        W_sl[i] = Whid[(size_t)(o0 + o) * 640 + k0 + kk];
    }
    {
        int b = tid & 63, kc = tid >> 6;
#pragma unroll
        for (int j = 0; j < 20; ++j) {
            int kk = kc * 20 + j;
            fin_sl[b * 81 + kk] = fin[b * 640 + k0 + kk];
        }
    }
    __syncthreads();

    int b = tid & 63, g = tid >> 6;
    float a0 = 0.f, a1 = 0.f;
    for (int kk = 0; kk < 80; kk += 4) {
        f32x4 w0 = *(const f32x4*)&W_sl[(g * 2) * 80 + kk];
        f32x4 w1 = *(const f32x4*)&W_sl[(g * 2 + 1) * 80 + kk];
        float f0 = fin_sl[b * 81 + kk + 0];
        float f1 = fin_sl[b * 81 + kk + 1];
        float f2 = fin_sl[b * 81 + kk + 2];
        float f3 = fin_sl[b * 81 + kk + 3];
        a0 += f0 * w0.x + f1 * w0.y + f2 * w0.z + f3 * w0.w;
        a1 += f0 * w1.x + f1 * w1.y + f2 * w1.z + f3 * w1.w;
    }
    paccum[kg * 16384 + b * 256 + o0 + g * 2 + 0] = a0;
    paccum[kg * 16384 + b * 256 + o0 + g * 2 + 1] = a1;
}

// ================= K5: gen GEMM + out_hidden, 256 blocks (sg 32 x bh 8) =================
__global__ __launch_bounds__(256) void k_gensum(const float* __restrict__ paccum,
                                                const float* __restrict__ bhid,
                                                const float* __restrict__ Wout,
                                                const float* __restrict__ bout,
                                                float* __restrict__ out_hidden,
                                                float* __restrict__ gen) {
    __shared__ __align__(16) float WoutL[4 * 256];
    __shared__ float hid_ld[8 * 257];
    __shared__ float boutL[4];
    int sg = blockIdx.x >> 3, bh = blockIdx.x & 7;
    int tid = threadIdx.x;
    int b0 = bh * 8;

    for (int i = tid; i < 4 * 256; i += 256)
        WoutL[i] = Wout[(size_t)(sg * 4 + (i >> 8)) * HH + (i & 255)];
    if (tid < 4) boutL[tid] = bout[sg * 4 + tid];

#pragma unroll
    for (int it = 0; it < 8; ++it) {
        int bidx = (b0 + it) * 256 + tid;
        float v = ((paccum[0 * 16384 + bidx] + paccum[1 * 16384 + bidx])
                 + (paccum[2 * 16384 + bidx] + paccum[3 * 16384 + bidx]))
                + ((paccum[4 * 16384 + bidx] + paccum[5 * 16384 + bidx])
                 + (paccum[6 * 16384 + bidx] + paccum[7 * 16384 + bidx]))
                + bhid[tid];
        hid_ld[it * 257 + tid] = fmaxf(v, 0.f);
    }
    __syncthreads();

    if (sg == 0) {
#pragma unroll
        for (int it = 0; it < 8; ++it)
            out_hidden[(size_t)(b0 + it) * HH + tid] = hid_ld[it * 257 + tid];
    }

    {
        int oi = tid >> 3, kt = tid & 7;
        int sq = oi >> 3, bq = oi & 7;
        float acc = 0.f;
#pragma unroll 8
        for (int jj = 0; jj < 32; ++jj) {
            int k = kt * 32 + ((jj + 4 * kt) & 31);
            acc += hid_ld[bq * 257 + k] * WoutL[sq * 256 + k];
        }
        acc += __shfl_xor(acc, 1, 64);
        acc += __shfl_xor(acc, 2, 64);
        acc += __shfl_xor(acc, 4, 64);
        if (kt == 0)
            gen[(size_t)(b0 + bq) * SS + sg * 4 + sq] = fmaxf(acc + boutL[sq], 0.f);
    }
}

// ================= K6: probas stats + streaming fill + scatter, half-rows =========
__global__ __launch_bounds__(256) void k_fill(const int* __restrict__ slot,
                                              const int* __restrict__ fidx,
                                              const float* __restrict__ gen,
                                              float* __restrict__ out) {
    __shared__ float genl[SS], genacc[SS], pv[SS];
    __shared__ float red[12];
    __shared__ int fidxL[SS], cls[SS];
    int bx = blockIdx.x;
    int row = bx >> 1, half = bx & 1;
    int l = row >> 6, b = row & 63;
    int tid = threadIdx.x;
    int lane = tid & 63, wv = tid >> 6;

    if (tid < SS) {
        genl[tid] = gen[(size_t)b * SS + tid];
        fidxL[tid] = fidx[l * SS + tid];
        cls[tid] = slot[l * SS + tid];
        genacc[tid] = 0.f;
    }
    __syncthreads();
    if (tid < SS) atomicAdd(&genacc[fidxL[tid]], genl[tid]);
    __syncthreads();

    float mg = 0.f;
    bool first = false;
    if (tid < SS) {
        first = (fidxL[tid] == tid);
        mg = -0.01f + genacc[tid];
    }
    float mx = first ? mg : -3.0e38f;
#pragma unroll
    for (int off = 32; off; off >>= 1) mx = fmaxf(mx, __shfl_xor(mx, off, 64));
    if (lane == 0) red[wv] = mx;
    __syncthreads();
    float M = fmaxf(red[0], red[1]);
    float e = first ? expf(mg - M) : 0.f;
    float s1 = e, s2 = first ? 1.f : 0.f;
#pragma unroll
    for (int off = 32; off; off >>= 1) {
        s1 += __shfl_xor(s1, off, 64);
        s2 += __shfl_xor(s2, off, 64);
    }
    if (lane == 0) { red[4 + wv] = s1; red[8 + wv] = s2; }
    __syncthreads();
    float sumHits = red[4] + red[5];
    float cntv = red[8] + red[9];
    float base = expf(-0.01f - M);
    float inv = 1.f / (((float)VV - cntv) * base + sumHits);
    float pb = base * inv;
    if (tid < SS) pv[tid] = first ? e * inv : -1.f;
    __syncthreads();

    float* rowp = out + BB * HH + ((size_t)(l * BB + b)) * VV;
    float4 p4 = make_float4(pb, pb, pb, pb);
    float4* row4 = (float4*)rowp + half * (VV / 8);
#pragma unroll 4
    for (int idx = tid; idx < VV / 8; idx += 256) row4[idx] = p4;
    __syncthreads();
    if (tid < SS && pv[tid] >= 0.f) {
        int c = cls[tid];
        int lo = half * (VV / 2);
        if (c >= lo && c < lo + VV / 2) rowp[c] = pv[tid];
    }
}

extern "C" void kernel_launch(void* const* d_in, const int* in_sizes, int n_in,
                              void* d_out, int out_size, void* d_ws, size_t ws_size,
                              hipStream_t stream) {
    const float* u_enc       = (const float*)d_in[0];
    const float* last_hidden = (const float*)d_in[1];
    const int*   z_tm1       = (const int*)d_in[2];
    const int*   slot        = (const int*)d_in[3];
    const float* emb_W       = (const float*)d_in[4];
    const float* ctrl_W      = (const float*)d_in[5];
    const float* ctrl_b      = (const float*)d_in[6];
    const float* attn_W      = (const float*)d_in[7];
    const float* attn_b      = (const float*)d_in[8];
    const float* attn_v      = (const float*)d_in[9];
    const float* Whid        = (const float*)d_in[10];
    const float* bhid        = (const float*)d_in[11];
    const float* Wout        = (const float*)d_in[12];
    const float* bout        = (const float*)d_in[13];
    float* out = (float*)d_out;
    float* ws = (float*)d_ws;

    float* mArr    = ws;              // 1024
    float* dArr    = ws + 1024;       // 1024
    float* hWp     = ws + 2048;       // 32768
    float* embed   = ws + 34816;      // 8192
    float* gen     = ws + 43008;      // 8192
    unsigned short* Bs = (unsigned short*)(ws + 51200);  // 65536 bf16
    float* partial = ws + 83968;      // 262144  ([b][c][h])
    float* fin     = ws + 346112;     // 40960
    float* paccum  = ws + 387072;     // 131072
    int*   fidx    = (int*)(ws + 518144);  // 2048 ints

    k_pre<<<232, 256, 0, stream>>>(last_hidden, attn_W, attn_b, z_tm1, emb_W, ctrl_W,
                                   ctrl_b, slot, hWp, embed, Bs, fidx);
    dim3 gs(16, BB);
    k_sctx<<<gs, 256, 0, stream>>>(u_enc, Bs, attn_v, hWp, partial, mArr, dArr);
    k_fin<<<BB * 4, 256, 0, stream>>>(partial, mArr, dArr, embed, last_hidden, fin);
    k_hid<<<256, 256, 0, stream>>>(fin, Whid, paccum);
    k_gensum<<<256, 256, 0, stream>>>(paccum, bhid, Wout, bout, out, gen);
    k_fill<<<LL * BB * 2, 256, 0, stream>>>(slot, fidx, gen, out);
}